// Round 1
// 288.118 us; speedup vs baseline: 1.0772x; 1.0772x over previous
//
#include <hip/hip_runtime.h>

#define NPIX 4096
#define SCALE 0.125f

typedef _Float16 half8 __attribute__((ext_vector_type(8)));
typedef float floatx4 __attribute__((ext_vector_type(4)));

// async global->LDS, 16B per lane. lds must be wave-uniform; data lands at
// lds + lane*16 (gfx950 semantics, learn_hip m97/m104).
__device__ __forceinline__ void async16(void* lds, const void* g) {
  __builtin_amdgcn_global_load_lds(
      (const __attribute__((address_space(1))) unsigned int*)(uintptr_t)g,
      (__attribute__((address_space(3))) unsigned int*)(unsigned)(uintptr_t)lds,
      16, 0, 0);
}

// ---------------------------------------------------------------------------
// split fp32 -> hi/lo fp16 (a = hi + lo, ~21 mantissa bits kept)
// ---------------------------------------------------------------------------
__global__ __launch_bounds__(256) void split16_kernel(const float* __restrict__ w,
                                                      _Float16* __restrict__ hi,
                                                      _Float16* __restrict__ lo, int n) {
  int i = blockIdx.x * 256 + threadIdx.x;
  if (i < n) {
    float v = w[i];
    _Float16 h = (_Float16)v;
    hi[i] = h;
    lo[i] = (_Float16)(v - (float)h);
  }
}

// ---------------------------------------------------------------------------
// x[b][256][4096] fp32 -> xt[b][4096][256] fp16 (K-contiguous for B-operand)
// ---------------------------------------------------------------------------
__global__ __launch_bounds__(256) void transpose16_kernel(const float* __restrict__ x,
                                                          _Float16* __restrict__ xt) {
  __shared__ float t[64][65];
  const int n0 = blockIdx.x * 64, c0 = blockIdx.y * 64, b = blockIdx.z;
  const float* xp = x + (long)b * 256 * NPIX;
  const int tid = threadIdx.x;
  const int r = tid >> 4, c4 = (tid & 15) * 4;
#pragma unroll
  for (int p = 0; p < 4; p++) {
    float4 v = *(const float4*)&xp[(long)(c0 + r + p * 16) * NPIX + n0 + c4];
    t[r + p * 16][c4 + 0] = v.x;
    t[r + p * 16][c4 + 1] = v.y;
    t[r + p * 16][c4 + 2] = v.z;
    t[r + p * 16][c4 + 3] = v.w;
  }
  __syncthreads();
  const int n = tid >> 2, cg = (tid & 3) * 16;
  alignas(16) _Float16 o[16];
#pragma unroll
  for (int i = 0; i < 16; i++) o[i] = (_Float16)t[cg + i][n];
  _Float16* dst = &xt[((long)b * NPIX + n0 + n) * 256 + c0 + cg];
  *(float4*)dst = *(float4*)&o[0];
  *(float4*)(dst + 8) = *(float4*)&o[8];
}

// ---------------------------------------------------------------------------
// MFMA GEMM: C[b][M][4096] = (Ah+Al)[M][256] * Bt[b][4096][256]^T (+bias)
// LDS 16B-block XOR swizzle: block' = block ^ ((row>>1)&3). global_load_lds
// writes linearly, so the swizzle is applied to the global SOURCE column and
// compensated on the ds_read side -> b128 frag reads are bank-conflict-free.
// ---------------------------------------------------------------------------
template <bool HAS_BIAS>
__global__ __launch_bounds__(256) void mfma_gemm(const _Float16* __restrict__ Ahp,
                                                 const _Float16* __restrict__ Alp,
                                                 const _Float16* __restrict__ Bt,
                                                 float* __restrict__ C,
                                                 const float* __restrict__ bias,
                                                 long sB, long sC) {
  __shared__ _Float16 sAh[128 * 32];
  __shared__ _Float16 sAl[128 * 32];
  __shared__ _Float16 sBt[128 * 32];
  const int tid = threadIdx.x;
  const int n0 = blockIdx.x * 128, m0 = blockIdx.y * 128;
  const _Float16* Bp = Bt + (long)blockIdx.z * sB;
  float* Cp = C + (long)blockIdx.z * sC;
  const int wv = tid >> 6, l = tid & 63;
  const int r16 = l & 15, q = l >> 4;
  const int mb = (wv >> 1) * 64, nb = (wv & 1) * 64;
  const int r1 = tid >> 2;
  // swizzled source column block (key identical for r1 and r1+64)
  const int o1 = ((tid & 3) * 8) ^ (((r1 >> 1) & 3) * 8);
  const int r2 = r1 + 64;
  const int ldsc1 = (wv * 64) * 8;
  const int ldsc2 = (256 + wv * 64) * 8;
  // swizzled read column (key independent of mb/nb/i since those are mult. of 8 rows)
  const int q8 = (q * 8) ^ (((r16 >> 1) & 3) * 8);

  floatx4 acc[4][4];
#pragma unroll
  for (int i = 0; i < 4; i++)
#pragma unroll
    for (int j = 0; j < 4; j++) acc[i][j] = (floatx4){0.f, 0.f, 0.f, 0.f};

  for (int kt = 0; kt < 8; kt++) {
    const int k0 = kt * 32;
    async16(&sAh[ldsc1], &Ahp[(long)(m0 + r1) * 256 + k0 + o1]);
    async16(&sAh[ldsc2], &Ahp[(long)(m0 + r2) * 256 + k0 + o1]);
    async16(&sAl[ldsc1], &Alp[(long)(m0 + r1) * 256 + k0 + o1]);
    async16(&sAl[ldsc2], &Alp[(long)(m0 + r2) * 256 + k0 + o1]);
    async16(&sBt[ldsc1], &Bp[(long)(n0 + r1) * 256 + k0 + o1]);
    async16(&sBt[ldsc2], &Bp[(long)(n0 + r2) * 256 + k0 + o1]);
    __syncthreads();
    half8 fa[4], flo[4], fb[4];
#pragma unroll
    for (int i = 0; i < 4; i++) {
      fa[i] = *(const half8*)&sAh[(mb + i * 16 + r16) * 32 + q8];
      flo[i] = *(const half8*)&sAl[(mb + i * 16 + r16) * 32 + q8];
      fb[i] = *(const half8*)&sBt[(nb + i * 16 + r16) * 32 + q8];
    }
#pragma unroll
    for (int i = 0; i < 4; i++)
#pragma unroll
      for (int j = 0; j < 4; j++) {
        acc[i][j] = __builtin_amdgcn_mfma_f32_16x16x32_f16(fa[i], fb[j], acc[i][j], 0, 0, 0);
        acc[i][j] = __builtin_amdgcn_mfma_f32_16x16x32_f16(flo[i], fb[j], acc[i][j], 0, 0, 0);
      }
    __syncthreads();
  }
#pragma unroll
  for (int i = 0; i < 4; i++) {
    const int mrow = m0 + mb + i * 16 + q * 4;
#pragma unroll
    for (int t = 0; t < 4; t++) {
      float bz = HAS_BIAS ? bias[mrow + t] : 0.f;
#pragma unroll
      for (int j = 0; j < 4; j++) {
        Cp[(long)(mrow + t) * NPIX + n0 + nb + j * 16 + r16] = acc[i][j][t] + bz;
      }
    }
  }
}

// ---------------------------------------------------------------------------
// FUSED: per (n-chunk=128, head, batch) compute the [k_head|v_head] 128x128
// GEMM tile entirely in-block, then -- without touching HBM -- form the
// context partial via a second MFMA:
//   pbuf[bh][chunk][d][e] = sum_{n in chunk} exp(k[d][n]) * v[e][n]
//   rsbuf[bh][chunk][d]   = sum_{n in chunk} exp(k[d][n])
// k,v are never written to HBM (saves 134 MB write + 134 MB read vs the old
// qkv-materialize + context_mfma pipeline). exp() is applied to the same fp32
// accumulator value as before -> numerics unchanged.
// ---------------------------------------------------------------------------
__global__ __launch_bounds__(256) void kv_ctx_gemm(const _Float16* __restrict__ Ahp,
                                                   const _Float16* __restrict__ Alp,
                                                   const _Float16* __restrict__ Bt,
                                                   float* __restrict__ pbuf,
                                                   float* __restrict__ rsbuf) {
  union alignas(16) KVU {
    struct {
      _Float16 Ah[128 * 32];
      _Float16 Al[128 * 32];
      _Float16 Bt[128 * 32];
    } st;                        // 24 KB, main-loop staging
    _Float16 ev[128][136];       // 34 KB, epilogue: rows 0..63 exp(k), 64..127 v
  };
  __shared__ KVU u;
  const int tid = threadIdx.x;
  const int chunk = blockIdx.x;  // 0..31, n-chunk of 128
  const int hi = blockIdx.y;     // head 0..3
  const int b = blockIdx.z;
  const int n0 = chunk * 128;
  const _Float16* Bp = Bt + (long)b * NPIX * 256;
  const int wv = tid >> 6, l = tid & 63;
  const int r16 = l & 15, q = l >> 4;
  const int mb = (wv >> 1) * 64, nb = (wv & 1) * 64;
  const int r1 = tid >> 2;
  const int o1 = ((tid & 3) * 8) ^ (((r1 >> 1) & 3) * 8);
  const int ldsc1 = (wv * 64) * 8;
  const int ldsc2 = (256 + wv * 64) * 8;
  const int q8 = (q * 8) ^ (((r16 >> 1) & 3) * 8);
  // A rows: local 0..63 = k[head hi], 64..127 = v[head hi]
  const long gAk = (long)(256 + hi * 64 + r1) * 256;
  const long gAv = (long)(512 + hi * 64 + r1) * 256;

  floatx4 acc[4][4];
#pragma unroll
  for (int i = 0; i < 4; i++)
#pragma unroll
    for (int j = 0; j < 4; j++) acc[i][j] = (floatx4){0.f, 0.f, 0.f, 0.f};

  for (int kt = 0; kt < 8; kt++) {
    const int k0 = kt * 32;
    async16(&u.st.Ah[ldsc1], &Ahp[gAk + k0 + o1]);
    async16(&u.st.Ah[ldsc2], &Ahp[gAv + k0 + o1]);
    async16(&u.st.Al[ldsc1], &Alp[gAk + k0 + o1]);
    async16(&u.st.Al[ldsc2], &Alp[gAv + k0 + o1]);
    async16(&u.st.Bt[ldsc1], &Bp[(long)(n0 + r1) * 256 + k0 + o1]);
    async16(&u.st.Bt[ldsc2], &Bp[(long)(n0 + 64 + r1) * 256 + k0 + o1]);
    __syncthreads();
    half8 fa[4], flo[4], fb[4];
#pragma unroll
    for (int i = 0; i < 4; i++) {
      fa[i] = *(const half8*)&u.st.Ah[(mb + i * 16 + r16) * 32 + q8];
      flo[i] = *(const half8*)&u.st.Al[(mb + i * 16 + r16) * 32 + q8];
      fb[i] = *(const half8*)&u.st.Bt[(nb + i * 16 + r16) * 32 + q8];
    }
#pragma unroll
    for (int i = 0; i < 4; i++)
#pragma unroll
      for (int j = 0; j < 4; j++) {
        acc[i][j] = __builtin_amdgcn_mfma_f32_16x16x32_f16(fa[i], fb[j], acc[i][j], 0, 0, 0);
        acc[i][j] = __builtin_amdgcn_mfma_f32_16x16x32_f16(flo[i], fb[j], acc[i][j], 0, 0, 0);
      }
    __syncthreads();
  }

  // ---- epilogue: acc -> exp(k)/v fp16 tile in LDS (stride 136: 2-way max) ----
  const bool is_k = (mb == 0);
#pragma unroll
  for (int i = 0; i < 4; i++) {
    const int row = mb + i * 16 + q * 4;
#pragma unroll
    for (int j = 0; j < 4; j++) {
      const int col = nb + j * 16 + r16;
#pragma unroll
      for (int t = 0; t < 4; t++) {
        const float vv0 = acc[i][j][t];
        u.ev[row + t][col] = (_Float16)(is_k ? __expf(vv0) : vv0);
      }
    }
  }
  __syncthreads();

  // ---- context partial: D[d][e] = sum_n exp(k[d][n]) v[e][n], K = 128 ----
  floatx4 c2[4];
#pragma unroll
  for (int j = 0; j < 4; j++) c2[j] = (floatx4){0.f, 0.f, 0.f, 0.f};
  float rs = 0.f;
#pragma unroll
  for (int ks = 0; ks < 4; ks++) {
    half8 a = *(const half8*)&u.ev[wv * 16 + r16][ks * 32 + q * 8];
#pragma unroll
    for (int ii = 0; ii < 8; ii++) rs += (float)a[ii];
#pragma unroll
    for (int j = 0; j < 4; j++) {
      half8 bv = *(const half8*)&u.ev[64 + j * 16 + r16][ks * 32 + q * 8];
      c2[j] = __builtin_amdgcn_mfma_f32_16x16x32_f16(a, bv, c2[j], 0, 0, 0);
    }
  }
  // row-sum of exp(k): combine the 4 q-lanes holding row (wv*16 + r16)
  rs += __shfl_xor(rs, 16, 64);
  rs += __shfl_xor(rs, 32, 64);
  const int bh = b * 4 + hi;
  float* pp = pbuf + ((long)bh * 32 + chunk) * 4096;
#pragma unroll
  for (int j = 0; j < 4; j++)
#pragma unroll
    for (int reg = 0; reg < 4; reg++)
      pp[(wv * 16 + q * 4 + reg) * 64 + j * 16 + r16] = c2[j][reg];
  if (l < 16) rsbuf[((long)bh * 32 + chunk) * 64 + wv * 16 + r16] = rs;
}

// ---------------------------------------------------------------------------
// ctx[bh][e4096] = sum over 32 chunk-partials (deterministic, no atomics)
// ---------------------------------------------------------------------------
__global__ __launch_bounds__(256) void reduce_ctx(const float* __restrict__ pbuf,
                                                  float* __restrict__ ctx) {
  int g = blockIdx.x * 256 + threadIdx.x;  // 0..262143
  int bh = g >> 12, e = g & 4095;
  const float* pp = pbuf + ((long)bh * 32) * 4096 + e;
  float s = 0.f;
#pragma unroll
  for (int c = 0; c < 32; c++) s += pp[(long)c * 4096];
  ctx[g] = s;
}

// ---------------------------------------------------------------------------
// kinvz[bh*64+d] = 1 / sum over 32 chunk row-sums
// ---------------------------------------------------------------------------
__global__ __launch_bounds__(256) void zinv_kernel(const float* __restrict__ rsbuf,
                                                   float* __restrict__ kinvz) {
  int g = blockIdx.x * 256 + threadIdx.x;  // 0..4095 = bh*64 + d
  int bh = g >> 6, d = g & 63;
  const float* rp = rsbuf + (long)bh * 32 * 64 + d;
  float s = 0.f;
#pragma unroll
  for (int c = 0; c < 32; c++) s += rp[c * 64];
  kinvz[g] = 1.0f / s;
}

// ---------------------------------------------------------------------------
// fused q-softmax + attention out (LDS-resident q tile; shift-free softmax):
// out[b][n][h*64+e] (fp16) = sum_d ctx[d][e] * (exp(q[d,n])/S_n * SCALE * invZ_d)
// ---------------------------------------------------------------------------
__global__ __launch_bounds__(256, 2) void attnout_kernel(const float* __restrict__ qkv,
                                                         const float* __restrict__ ctx,
                                                         const float* __restrict__ kinvz,
                                                         _Float16* __restrict__ attn) {
  __shared__ float sq[64][260];
  const int nc = blockIdx.x;  // n-chunk of 256
  const int h = blockIdx.y, b = blockIdx.z;
  const float* qp = qkv + ((long)b * 768 + h * 64) * NPIX + nc * 256;
  const int tid = threadIdx.x;
#pragma unroll
  for (int p = 0; p < 16; p++) {
    int idx = tid + p * 256;     // 0..4095 float4s
    int row = idx >> 6;          // 0..63
    int c4 = (idx & 63) * 4;     // 0..252
    *(float4*)&sq[row][c4] = *(const float4*)&qp[(long)row * NPIX + c4];
  }
  __syncthreads();
  const int n = tid;
  float s = 0.f;
#pragma unroll
  for (int d = 0; d < 64; d++) {
    float e = __expf(sq[d][n]);
    sq[d][n] = e;  // own column only: no race
    s += e;
  }
  const float* cp = ctx + (long)(b * 4 + h) * 4096;
  const float* zp = kinvz + (b * 4 + h) * 64;
  const float r = SCALE / s;
  float acc[64];
#pragma unroll
  for (int e = 0; e < 64; e++) acc[e] = 0.f;
  for (int d = 0; d < 64; d++) {
    float pe = sq[d][n] * (r * zp[d]);
#pragma unroll
    for (int e = 0; e < 64; e++) acc[e] = fmaf(cp[d * 64 + e], pe, acc[e]);
  }
  alignas(16) _Float16 tmp[64];
#pragma unroll
  for (int e = 0; e < 64; e++) tmp[e] = (_Float16)acc[e];
  _Float16* op = attn + (long)b * 768 * NPIX * 2 + ((long)nc * 256 + n) * 256 + h * 64;
#pragma unroll
  for (int p = 0; p < 8; p++) ((float4*)op)[p] = ((float4*)tmp)[p];
}

extern "C" void kernel_launch(void* const* d_in, const int* in_sizes, int n_in,
                              void* d_out, int out_size, void* d_ws, size_t ws_size,
                              hipStream_t stream) {
  const float* x = (const float*)d_in[0];      // [16][256][4096]
  const float* w_qkv = (const float*)d_in[1];  // [768][256]
  const float* w_out = (const float*)d_in[2];  // [256][256]
  const float* b_out = (const float*)d_in[3];  // [256]
  float* out = (float*)d_out;                  // [16][256][4096]

  float* qkv = (float*)d_ws;                          // 192 MB fp32 (only q region written now)
  float* ctx = qkv + (long)16 * 768 * NPIX;           // 64bh*4096 = 1 MB
  _Float16* wq_hi = (_Float16*)(ctx + 16 * 4 * 64 * 64);
  _Float16* wq_lo = wq_hi + 768 * 256;
  _Float16* wo_hi = wq_lo + 768 * 256;
  _Float16* wo_lo = wo_hi + 256 * 256;
  float* kinvz = (float*)(wo_lo + 256 * 256);         // 64bh*64 = 4096 floats
  float* rsbuf = qkv + (long)256 * NPIX;              // dead k-region of batch 0: 64bh*32c*64 = 512 KB
  _Float16* xt = (_Float16*)d_out;                    // d_out[0..32MB) (dead until final GEMM)
  float* pbuf = (float*)d_out + (1 << 23);            // d_out[32MB..64MB): 64bh*32c*4096 floats
  _Float16* attn16 = (_Float16*)(qkv + (long)512 * NPIX);  // dead v-region of qkv

  split16_kernel<<<768, 256, 0, stream>>>(w_qkv, wq_hi, wq_lo, 768 * 256);
  split16_kernel<<<256, 256, 0, stream>>>(w_out, wo_hi, wo_lo, 256 * 256);
  transpose16_kernel<<<dim3(64, 4, 16), 256, 0, stream>>>(x, xt);
  // q = w_q @ x only (rows 0..255); k,v never touch HBM
  mfma_gemm<false><<<dim3(32, 2, 16), 256, 0, stream>>>(
      wq_hi, wq_lo, xt, qkv, nullptr, (long)NPIX * 256, (long)768 * NPIX);
  // fused k/v GEMM + exp(k)@v^T context partials + row-sums, per (chunk, head, b)
  kv_ctx_gemm<<<dim3(32, 4, 16), 256, 0, stream>>>(wq_hi, wq_lo, xt, pbuf, rsbuf);
  reduce_ctx<<<1024, 256, 0, stream>>>(pbuf, ctx);
  zinv_kernel<<<16, 256, 0, stream>>>(rsbuf, kinvz);
  // fused q-softmax + ctx^T@q, fp16 transposed output into dead v-region
  attnout_kernel<<<dim3(16, 4, 16), 256, 0, stream>>>(qkv, ctx, kinvz, attn16);
  // final = w_out @ attn + b_out
  mfma_gemm<true><<<dim3(32, 2, 16), 256, 0, stream>>>(
      wo_hi, wo_lo, attn16, out, b_out, (long)768 * NPIX * 2, (long)256 * NPIX);
}

// Round 2
// 232.053 us; speedup vs baseline: 1.3374x; 1.2416x over previous
//
#include <hip/hip_runtime.h>

#define NPIX 4096
#define SCALE 0.125f

typedef _Float16 half8 __attribute__((ext_vector_type(8)));
typedef _Float16 half4 __attribute__((ext_vector_type(4)));
typedef float floatx4 __attribute__((ext_vector_type(4)));

// async global->LDS, 16B per lane. lds must be wave-uniform; data lands at
// lds + lane*16 (gfx950 semantics, learn_hip m97/m104).
__device__ __forceinline__ void async16(void* lds, const void* g) {
  __builtin_amdgcn_global_load_lds(
      (const __attribute__((address_space(1))) unsigned int*)(uintptr_t)g,
      (__attribute__((address_space(3))) unsigned int*)(unsigned)(uintptr_t)lds,
      16, 0, 0);
}

// ---------------------------------------------------------------------------
// split fp32 -> hi/lo fp16 (a = hi + lo, ~21 mantissa bits kept)
// ---------------------------------------------------------------------------
__global__ __launch_bounds__(256) void split16_kernel(const float* __restrict__ w,
                                                      _Float16* __restrict__ hi,
                                                      _Float16* __restrict__ lo, int n) {
  int i = blockIdx.x * 256 + threadIdx.x;
  if (i < n) {
    float v = w[i];
    _Float16 h = (_Float16)v;
    hi[i] = h;
    lo[i] = (_Float16)(v - (float)h);
  }
}

// ---------------------------------------------------------------------------
// x[b][256][4096] fp32 -> xt[b][4096][256] fp16 (K-contiguous for B-operand)
// ---------------------------------------------------------------------------
__global__ __launch_bounds__(256) void transpose16_kernel(const float* __restrict__ x,
                                                          _Float16* __restrict__ xt) {
  __shared__ float t[64][65];
  const int n0 = blockIdx.x * 64, c0 = blockIdx.y * 64, b = blockIdx.z;
  const float* xp = x + (long)b * 256 * NPIX;
  const int tid = threadIdx.x;
  const int r = tid >> 4, c4 = (tid & 15) * 4;
#pragma unroll
  for (int p = 0; p < 4; p++) {
    float4 v = *(const float4*)&xp[(long)(c0 + r + p * 16) * NPIX + n0 + c4];
    t[r + p * 16][c4 + 0] = v.x;
    t[r + p * 16][c4 + 1] = v.y;
    t[r + p * 16][c4 + 2] = v.z;
    t[r + p * 16][c4 + 3] = v.w;
  }
  __syncthreads();
  const int n = tid >> 2, cg = (tid & 3) * 16;
  alignas(16) _Float16 o[16];
#pragma unroll
  for (int i = 0; i < 16; i++) o[i] = (_Float16)t[cg + i][n];
  _Float16* dst = &xt[((long)b * NPIX + n0 + n) * 256 + c0 + cg];
  *(float4*)dst = *(float4*)&o[0];
  *(float4*)(dst + 8) = *(float4*)&o[8];
}

// ---------------------------------------------------------------------------
// FUSED q-GEMM + column softmax over d:
//   acc = (Wq_hi+Wq_lo)[128 rows = 2 heads] @ xt^T  (split-A MFMA, fp32)
//   P[n][c] = exp(acc)/sum_d exp(acc)  per (head, n), written fp16 into
//   PT[b][s][4096][128] (s = c-half = m0>>7), coalesced via swizzled LDS tile.
// q never touches HBM in fp32.
// ---------------------------------------------------------------------------
__global__ __launch_bounds__(256) void q_gemm_softmax(const _Float16* __restrict__ Ahp,
                                                      const _Float16* __restrict__ Alp,
                                                      const _Float16* __restrict__ Bt,
                                                      _Float16* __restrict__ PT) {
  union alignas(16) QU {
    struct {
      _Float16 Ah[128 * 32];
      _Float16 Al[128 * 32];
      _Float16 Bt[128 * 32];
    } st;                     // 24 KB, main-loop staging
    _Float16 pt[128][128];    // 32 KB, epilogue P-tile (XOR-swizzled cols)
  };
  __shared__ QU u;
  const int tid = threadIdx.x;
  const int n0 = blockIdx.x * 128, m0 = blockIdx.y * 128;
  const int bz = blockIdx.z;
  const _Float16* Bp = Bt + (long)bz * NPIX * 256;
  const int wv = tid >> 6, l = tid & 63;
  const int r16 = l & 15, q = l >> 4;
  const int mb = (wv >> 1) * 64, nb = (wv & 1) * 64;
  const int r1 = tid >> 2;
  const int o1 = ((tid & 3) * 8) ^ (((r1 >> 1) & 3) * 8);
  const int r2 = r1 + 64;
  const int ldsc1 = (wv * 64) * 8;
  const int ldsc2 = (256 + wv * 64) * 8;
  const int q8 = (q * 8) ^ (((r16 >> 1) & 3) * 8);

  floatx4 acc[4][4];
#pragma unroll
  for (int i = 0; i < 4; i++)
#pragma unroll
    for (int j = 0; j < 4; j++) acc[i][j] = (floatx4){0.f, 0.f, 0.f, 0.f};

  for (int kt = 0; kt < 8; kt++) {
    const int k0 = kt * 32;
    async16(&u.st.Ah[ldsc1], &Ahp[(long)(m0 + r1) * 256 + k0 + o1]);
    async16(&u.st.Ah[ldsc2], &Ahp[(long)(m0 + r2) * 256 + k0 + o1]);
    async16(&u.st.Al[ldsc1], &Alp[(long)(m0 + r1) * 256 + k0 + o1]);
    async16(&u.st.Al[ldsc2], &Alp[(long)(m0 + r2) * 256 + k0 + o1]);
    async16(&u.st.Bt[ldsc1], &Bp[(long)(n0 + r1) * 256 + k0 + o1]);
    async16(&u.st.Bt[ldsc2], &Bp[(long)(n0 + r2) * 256 + k0 + o1]);
    __syncthreads();
    half8 fa[4], flo[4], fb[4];
#pragma unroll
    for (int i = 0; i < 4; i++) {
      fa[i] = *(const half8*)&u.st.Ah[(mb + i * 16 + r16) * 32 + q8];
      flo[i] = *(const half8*)&u.st.Al[(mb + i * 16 + r16) * 32 + q8];
      fb[i] = *(const half8*)&u.st.Bt[(nb + i * 16 + r16) * 32 + q8];
    }
#pragma unroll
    for (int i = 0; i < 4; i++)
#pragma unroll
      for (int j = 0; j < 4; j++) {
        acc[i][j] = __builtin_amdgcn_mfma_f32_16x16x32_f16(fa[i], fb[j], acc[i][j], 0, 0, 0);
        acc[i][j] = __builtin_amdgcn_mfma_f32_16x16x32_f16(flo[i], fb[j], acc[i][j], 0, 0, 0);
      }
    __syncthreads();
  }

  // ---- epilogue: per-column softmax over d (wave holds one head's 64 rows) ----
#pragma unroll
  for (int j = 0; j < 4; j++) {
    float s = 0.f;
#pragma unroll
    for (int i = 0; i < 4; i++)
#pragma unroll
      for (int t = 0; t < 4; t++) {
        float e = __expf(acc[i][j][t]);
        acc[i][j][t] = e;
        s += e;
      }
    s += __shfl_xor(s, 16, 64);
    s += __shfl_xor(s, 32, 64);
    const float rinv = 1.0f / s;
    const int nl = nb + j * 16 + r16;
    const int swz = (nl & 7) * 8;  // bank-spread: (q,nl&7) -> 32 distinct banks
#pragma unroll
    for (int i = 0; i < 4; i++) {
      half4 h4;
#pragma unroll
      for (int t = 0; t < 4; t++) h4[t] = (_Float16)(acc[i][j][t] * rinv);
      *(half4*)&u.pt[nl][(mb + i * 16 + q * 4) ^ swz] = h4;
    }
  }
  __syncthreads();
  // ---- dump P-tile: rows contiguous (PT row stride = 128 c), 1KB/wave-instr ----
  const int rbase = tid >> 4, c16 = tid & 15;
  _Float16* dst = PT + ((long)(bz * 2 + (m0 >> 7)) * NPIX + n0) * 128;
#pragma unroll
  for (int k = 0; k < 8; k++) {
    const int row = rbase + k * 16;
    const int chunk = c16 ^ (row & 7);
    float4 v = *(const float4*)&u.pt[row][chunk * 8];
    *(float4*)&dst[(long)row * 128 + c16 * 8] = v;
  }
}

// ---------------------------------------------------------------------------
// FUSED: per (n-chunk=128, head, batch) compute the [k_head|v_head] 128x128
// GEMM tile entirely in-block, then form the context partial via MFMA:
//   pbuf[bh][chunk][d][e] = sum_{n in chunk} exp(k[d][n]) * v[e][n]
//   rsbuf[bh][chunk][d]   = sum_{n in chunk} exp(k[d][n])
// ---------------------------------------------------------------------------
__global__ __launch_bounds__(256) void kv_ctx_gemm(const _Float16* __restrict__ Ahp,
                                                   const _Float16* __restrict__ Alp,
                                                   const _Float16* __restrict__ Bt,
                                                   float* __restrict__ pbuf,
                                                   float* __restrict__ rsbuf) {
  union alignas(16) KVU {
    struct {
      _Float16 Ah[128 * 32];
      _Float16 Al[128 * 32];
      _Float16 Bt[128 * 32];
    } st;                        // 24 KB, main-loop staging
    _Float16 ev[128][136];       // 34 KB, epilogue: rows 0..63 exp(k), 64..127 v
  };
  __shared__ KVU u;
  const int tid = threadIdx.x;
  const int chunk = blockIdx.x;  // 0..31, n-chunk of 128
  const int hi = blockIdx.y;     // head 0..3
  const int b = blockIdx.z;
  const int n0 = chunk * 128;
  const _Float16* Bp = Bt + (long)b * NPIX * 256;
  const int wv = tid >> 6, l = tid & 63;
  const int r16 = l & 15, q = l >> 4;
  const int mb = (wv >> 1) * 64, nb = (wv & 1) * 64;
  const int r1 = tid >> 2;
  const int o1 = ((tid & 3) * 8) ^ (((r1 >> 1) & 3) * 8);
  const int ldsc1 = (wv * 64) * 8;
  const int ldsc2 = (256 + wv * 64) * 8;
  const int q8 = (q * 8) ^ (((r16 >> 1) & 3) * 8);
  // A rows: local 0..63 = k[head hi], 64..127 = v[head hi]
  const long gAk = (long)(256 + hi * 64 + r1) * 256;
  const long gAv = (long)(512 + hi * 64 + r1) * 256;

  floatx4 acc[4][4];
#pragma unroll
  for (int i = 0; i < 4; i++)
#pragma unroll
    for (int j = 0; j < 4; j++) acc[i][j] = (floatx4){0.f, 0.f, 0.f, 0.f};

  for (int kt = 0; kt < 8; kt++) {
    const int k0 = kt * 32;
    async16(&u.st.Ah[ldsc1], &Ahp[gAk + k0 + o1]);
    async16(&u.st.Ah[ldsc2], &Ahp[gAv + k0 + o1]);
    async16(&u.st.Al[ldsc1], &Alp[gAk + k0 + o1]);
    async16(&u.st.Al[ldsc2], &Alp[gAv + k0 + o1]);
    async16(&u.st.Bt[ldsc1], &Bp[(long)(n0 + r1) * 256 + k0 + o1]);
    async16(&u.st.Bt[ldsc2], &Bp[(long)(n0 + 64 + r1) * 256 + k0 + o1]);
    __syncthreads();
    half8 fa[4], flo[4], fb[4];
#pragma unroll
    for (int i = 0; i < 4; i++) {
      fa[i] = *(const half8*)&u.st.Ah[(mb + i * 16 + r16) * 32 + q8];
      flo[i] = *(const half8*)&u.st.Al[(mb + i * 16 + r16) * 32 + q8];
      fb[i] = *(const half8*)&u.st.Bt[(nb + i * 16 + r16) * 32 + q8];
    }
#pragma unroll
    for (int i = 0; i < 4; i++)
#pragma unroll
      for (int j = 0; j < 4; j++) {
        acc[i][j] = __builtin_amdgcn_mfma_f32_16x16x32_f16(fa[i], fb[j], acc[i][j], 0, 0, 0);
        acc[i][j] = __builtin_amdgcn_mfma_f32_16x16x32_f16(flo[i], fb[j], acc[i][j], 0, 0, 0);
      }
    __syncthreads();
  }

  // ---- epilogue: acc -> exp(k)/v fp16 tile in LDS (stride 136: 2-way max) ----
  const bool is_k = (mb == 0);
#pragma unroll
  for (int i = 0; i < 4; i++) {
    const int row = mb + i * 16 + q * 4;
#pragma unroll
    for (int j = 0; j < 4; j++) {
      const int col = nb + j * 16 + r16;
#pragma unroll
      for (int t = 0; t < 4; t++) {
        const float vv0 = acc[i][j][t];
        u.ev[row + t][col] = (_Float16)(is_k ? __expf(vv0) : vv0);
      }
    }
  }
  __syncthreads();

  // ---- context partial: D[d][e] = sum_n exp(k[d][n]) v[e][n], K = 128 ----
  floatx4 c2[4];
#pragma unroll
  for (int j = 0; j < 4; j++) c2[j] = (floatx4){0.f, 0.f, 0.f, 0.f};
  float rs = 0.f;
#pragma unroll
  for (int ks = 0; ks < 4; ks++) {
    half8 a = *(const half8*)&u.ev[wv * 16 + r16][ks * 32 + q * 8];
#pragma unroll
    for (int ii = 0; ii < 8; ii++) rs += (float)a[ii];
#pragma unroll
    for (int j = 0; j < 4; j++) {
      half8 bv = *(const half8*)&u.ev[64 + j * 16 + r16][ks * 32 + q * 8];
      c2[j] = __builtin_amdgcn_mfma_f32_16x16x32_f16(a, bv, c2[j], 0, 0, 0);
    }
  }
  rs += __shfl_xor(rs, 16, 64);
  rs += __shfl_xor(rs, 32, 64);
  const int bh = b * 4 + hi;
  float* pp = pbuf + ((long)bh * 32 + chunk) * 4096;
#pragma unroll
  for (int j = 0; j < 4; j++)
#pragma unroll
    for (int reg = 0; reg < 4; reg++)
      pp[(wv * 16 + q * 4 + reg) * 64 + j * 16 + r16] = c2[j][reg];
  if (l < 16) rsbuf[((long)bh * 32 + chunk) * 64 + wv * 16 + r16] = rs;
}

// ---------------------------------------------------------------------------
// ctx[bh][4096] = sum over 32 chunk-partials (deterministic, no atomics)
// ---------------------------------------------------------------------------
__global__ __launch_bounds__(256) void reduce_ctx(const float* __restrict__ pbuf,
                                                  float* __restrict__ ctx) {
  int g = blockIdx.x * 256 + threadIdx.x;  // 0..262143
  int bh = g >> 12, e = g & 4095;
  const float* pp = pbuf + ((long)bh * 32) * 4096 + e;
  float s = 0.f;
#pragma unroll
  for (int c = 0; c < 32; c++) s += pp[(long)c * 4096];
  ctx[g] = s;
}

// ---------------------------------------------------------------------------
// kinvz[bh*64+d] = 1 / sum over 32 chunk row-sums
// ---------------------------------------------------------------------------
__global__ __launch_bounds__(256) void zinv_kernel(const float* __restrict__ rsbuf,
                                                   float* __restrict__ kinvz) {
  int g = blockIdx.x * 256 + threadIdx.x;  // 0..4095 = bh*64 + d
  int bh = g >> 6, d = g & 63;
  const float* rp = rsbuf + (long)bh * 32 * 64 + d;
  float s = 0.f;
#pragma unroll
  for (int c = 0; c < 32; c++) s += rp[c * 64];
  kinvz[g] = 1.0f / s;
}

// ---------------------------------------------------------------------------
// M_b[c][h*64+d] = SCALE * invZ[bh][d] * sum_e w_out[c][h*64+e] * ctx[bh][d][e]
// (folds the attention d-contraction into the final GEMM's A-operand).
// fp32 compute, hi/lo fp16 split output. grid (4 cq, 4 h, 16 b), 256 thr.
// ---------------------------------------------------------------------------
__global__ __launch_bounds__(256) void mctx_kernel(const float* __restrict__ w_out,
                                                   const float* __restrict__ ctx,
                                                   const float* __restrict__ kinvz,
                                                   _Float16* __restrict__ Mhi,
                                                   _Float16* __restrict__ Mlo) {
  __shared__ float sctxT[64][65];  // [e][d], +1 pad
  const int cq = blockIdx.x, h = blockIdx.y, b = blockIdx.z;
  const int bh = b * 4 + h;
  const float* cp = ctx + (long)bh * 4096;  // [d][e]
  const int tid = threadIdx.x;
  {
    const int d = tid >> 2, e0 = (tid & 3) * 16;
#pragma unroll
    for (int k = 0; k < 4; k++) {
      float4 v = *(const float4*)&cp[d * 64 + e0 + k * 4];
      sctxT[e0 + k * 4 + 0][d] = v.x;
      sctxT[e0 + k * 4 + 1][d] = v.y;
      sctxT[e0 + k * 4 + 2][d] = v.z;
      sctxT[e0 + k * 4 + 3][d] = v.w;
    }
  }
  __syncthreads();
  const int c = cq * 64 + (tid >> 2);
  const int d0 = (tid & 3) * 16;
  const float* wp = w_out + (long)c * 256 + h * 64;
  float acc[16];
#pragma unroll
  for (int i = 0; i < 16; i++) acc[i] = 0.f;
#pragma unroll
  for (int e4 = 0; e4 < 16; e4++) {
    float4 wv = *(const float4*)&wp[e4 * 4];
#pragma unroll
    for (int u2 = 0; u2 < 4; u2++) {
      const float we = ((const float*)&wv)[u2];
      const int e = e4 * 4 + u2;
#pragma unroll
      for (int dd = 0; dd < 16; dd++) acc[dd] = fmaf(we, sctxT[e][d0 + dd], acc[dd]);
    }
  }
  alignas(16) _Float16 hi16[16], lo16[16];
#pragma unroll
  for (int k4 = 0; k4 < 4; k4++) {
    float4 zv = *(const float4*)&kinvz[bh * 64 + d0 + k4 * 4];
#pragma unroll
    for (int u2 = 0; u2 < 4; u2++) {
      const int dd = k4 * 4 + u2;
      float v = acc[dd] * (SCALE * ((const float*)&zv)[u2]);
      _Float16 hh = (_Float16)v;
      hi16[dd] = hh;
      lo16[dd] = (_Float16)(v - (float)hh);
    }
  }
  _Float16* mh = Mhi + ((long)b * 256 + c) * 256 + h * 64 + d0;
  _Float16* ml = Mlo + ((long)b * 256 + c) * 256 + h * 64 + d0;
#pragma unroll
  for (int k = 0; k < 2; k++) {
    *(float4*)&mh[k * 8] = *(float4*)&hi16[k * 8];
    *(float4*)&ml[k * 8] = *(float4*)&lo16[k * 8];
  }
}

// ---------------------------------------------------------------------------
// final GEMM: out[b][256][4096] = (Mhi+Mlo)[b] @ PT[b]^T + b_out
// B layout: PT[b][s][4096][128], s = K-half (kt>>2).
// ---------------------------------------------------------------------------
__global__ __launch_bounds__(256) void out_gemm(const _Float16* __restrict__ Mhi,
                                                const _Float16* __restrict__ Mlo,
                                                const _Float16* __restrict__ PT,
                                                float* __restrict__ C,
                                                const float* __restrict__ bias) {
  __shared__ _Float16 sAh[128 * 32];
  __shared__ _Float16 sAl[128 * 32];
  __shared__ _Float16 sBt[128 * 32];
  const int tid = threadIdx.x;
  const int n0 = blockIdx.x * 128, m0 = blockIdx.y * 128;
  const int b = blockIdx.z;
  const _Float16* Ah = Mhi + (long)b * 65536;
  const _Float16* Al = Mlo + (long)b * 65536;
  float* Cp = C + (long)b * 256 * NPIX;
  const int wv = tid >> 6, l = tid & 63;
  const int r16 = l & 15, q = l >> 4;
  const int mb = (wv >> 1) * 64, nb = (wv & 1) * 64;
  const int r1 = tid >> 2;
  const int o1 = ((tid & 3) * 8) ^ (((r1 >> 1) & 3) * 8);
  const int r2 = r1 + 64;
  const int ldsc1 = (wv * 64) * 8;
  const int ldsc2 = (256 + wv * 64) * 8;
  const int q8 = (q * 8) ^ (((r16 >> 1) & 3) * 8);

  floatx4 acc[4][4];
#pragma unroll
  for (int i = 0; i < 4; i++)
#pragma unroll
    for (int j = 0; j < 4; j++) acc[i][j] = (floatx4){0.f, 0.f, 0.f, 0.f};

  for (int kt = 0; kt < 8; kt++) {
    const int k0 = kt * 32;
    async16(&sAh[ldsc1], &Ah[(long)(m0 + r1) * 256 + k0 + o1]);
    async16(&sAh[ldsc2], &Ah[(long)(m0 + r2) * 256 + k0 + o1]);
    async16(&sAl[ldsc1], &Al[(long)(m0 + r1) * 256 + k0 + o1]);
    async16(&sAl[ldsc2], &Al[(long)(m0 + r2) * 256 + k0 + o1]);
    const _Float16* Bk = PT + ((long)(b * 2 + (kt >> 2)) * NPIX + n0) * 128;
    async16(&sBt[ldsc1], &Bk[(long)r1 * 128 + (kt & 3) * 32 + o1]);
    async16(&sBt[ldsc2], &Bk[(long)(r1 + 64) * 128 + (kt & 3) * 32 + o1]);
    __syncthreads();
    half8 fa[4], flo[4], fb[4];
#pragma unroll
    for (int i = 0; i < 4; i++) {
      fa[i] = *(const half8*)&sAh[(mb + i * 16 + r16) * 32 + q8];
      flo[i] = *(const half8*)&sAl[(mb + i * 16 + r16) * 32 + q8];
      fb[i] = *(const half8*)&sBt[(nb + i * 16 + r16) * 32 + q8];
    }
#pragma unroll
    for (int i = 0; i < 4; i++)
#pragma unroll
      for (int j = 0; j < 4; j++) {
        acc[i][j] = __builtin_amdgcn_mfma_f32_16x16x32_f16(fa[i], fb[j], acc[i][j], 0, 0, 0);
        acc[i][j] = __builtin_amdgcn_mfma_f32_16x16x32_f16(flo[i], fb[j], acc[i][j], 0, 0, 0);
      }
    __syncthreads();
  }
#pragma unroll
  for (int i = 0; i < 4; i++) {
    const int mrow = m0 + mb + i * 16 + q * 4;
#pragma unroll
    for (int t = 0; t < 4; t++) {
      float bz = bias[mrow + t];
#pragma unroll
      for (int j = 0; j < 4; j++) {
        Cp[(long)(mrow + t) * NPIX + n0 + nb + j * 16 + r16] = acc[i][j][t] + bz;
      }
    }
  }
}

extern "C" void kernel_launch(void* const* d_in, const int* in_sizes, int n_in,
                              void* d_out, int out_size, void* d_ws, size_t ws_size,
                              hipStream_t stream) {
  const float* x = (const float*)d_in[0];      // [16][256][4096]
  const float* w_qkv = (const float*)d_in[1];  // [768][256]
  const float* w_out = (const float*)d_in[2];  // [256][256]
  const float* b_out = (const float*)d_in[3];  // [256]
  float* out = (float*)d_out;                  // [16][256][4096]

  // d_ws layout (all live ranges disjoint in time or space):
  _Float16* PT = (_Float16*)d_ws;                           // [16][2][4096][128] = 32 MB
  float* ctx = (float*)(PT + (long)16 * 2 * NPIX * 128);    // 64bh * 4096 = 1 MB
  float* kinvz = ctx + 64 * 4096;                           // 16 KB
  float* rsbuf = kinvz + 4096;                              // 64bh*32c*64 = 512 KB
  _Float16* wq_hi = (_Float16*)(rsbuf + 64 * 32 * 64);
  _Float16* wq_lo = wq_hi + 768 * 256;
  _Float16* Mhi = wq_lo + 768 * 256;                        // 16*256*256 fp16 = 2 MB
  _Float16* Mlo = Mhi + 16 * 256 * 256;                     // 2 MB
  // d_out scratch (dead until out_gemm writes it):
  _Float16* xt = (_Float16*)d_out;                          // [0..32MB)
  float* pbuf = (float*)d_out + (1 << 23);                  // [32MB..64MB)

  split16_kernel<<<768, 256, 0, stream>>>(w_qkv, wq_hi, wq_lo, 768 * 256);
  transpose16_kernel<<<dim3(64, 4, 16), 256, 0, stream>>>(x, xt);
  // fused k/v GEMM + exp(k)@v^T context partials + row-sums
  kv_ctx_gemm<<<dim3(32, 4, 16), 256, 0, stream>>>(wq_hi, wq_lo, xt, pbuf, rsbuf);
  reduce_ctx<<<1024, 256, 0, stream>>>(pbuf, ctx);
  zinv_kernel<<<16, 256, 0, stream>>>(rsbuf, kinvz);
  // fused q GEMM + softmax -> P fp16 (q fp32 never touches HBM)
  q_gemm_softmax<<<dim3(32, 2, 16), 256, 0, stream>>>(wq_hi, wq_lo, xt, PT);
  // M_b = w_out @ ctx^T * diag(SCALE*invZ): attention folded into final A
  mctx_kernel<<<dim3(4, 4, 16), 256, 0, stream>>>(w_out, ctx, kinvz, Mhi, Mlo);
  // final = M_b @ P_b + b_out
  out_gemm<<<dim3(32, 2, 16), 256, 0, stream>>>(Mhi, Mlo, PT, out, b_out);
}

// Round 3
// 214.550 us; speedup vs baseline: 1.4465x; 1.0816x over previous
//
#include <hip/hip_runtime.h>

#define NPIX 4096
#define SCALE 0.125f

typedef _Float16 half8 __attribute__((ext_vector_type(8)));
typedef _Float16 half4 __attribute__((ext_vector_type(4)));
typedef float floatx4 __attribute__((ext_vector_type(4)));

// async global->LDS, 16B per lane. lds must be wave-uniform; data lands at
// lds + lane*16 (gfx950 semantics, learn_hip m97/m104).
__device__ __forceinline__ void async16(void* lds, const void* g) {
  __builtin_amdgcn_global_load_lds(
      (const __attribute__((address_space(1))) unsigned int*)(uintptr_t)g,
      (__attribute__((address_space(3))) unsigned int*)(unsigned)(uintptr_t)lds,
      16, 0, 0);
}

// ---------------------------------------------------------------------------
// split fp32 -> hi/lo fp16 (a = hi + lo, ~21 mantissa bits kept)
// ---------------------------------------------------------------------------
__global__ __launch_bounds__(256) void split16_kernel(const float* __restrict__ w,
                                                      _Float16* __restrict__ hi,
                                                      _Float16* __restrict__ lo, int n) {
  int i = blockIdx.x * 256 + threadIdx.x;
  if (i < n) {
    float v = w[i];
    _Float16 h = (_Float16)v;
    hi[i] = h;
    lo[i] = (_Float16)(v - (float)h);
  }
}

// ---------------------------------------------------------------------------
// x[b][256][4096] fp32 -> xt[b][4096][256] fp16 (K-contiguous for B-operand)
// ---------------------------------------------------------------------------
__global__ __launch_bounds__(256) void transpose16_kernel(const float* __restrict__ x,
                                                          _Float16* __restrict__ xt) {
  __shared__ float t[64][65];
  const int n0 = blockIdx.x * 64, c0 = blockIdx.y * 64, b = blockIdx.z;
  const float* xp = x + (long)b * 256 * NPIX;
  const int tid = threadIdx.x;
  const int r = tid >> 4, c4 = (tid & 15) * 4;
#pragma unroll
  for (int p = 0; p < 4; p++) {
    float4 v = *(const float4*)&xp[(long)(c0 + r + p * 16) * NPIX + n0 + c4];
    t[r + p * 16][c4 + 0] = v.x;
    t[r + p * 16][c4 + 1] = v.y;
    t[r + p * 16][c4 + 2] = v.z;
    t[r + p * 16][c4 + 3] = v.w;
  }
  __syncthreads();
  const int n = tid >> 2, cg = (tid & 3) * 16;
  alignas(16) _Float16 o[16];
#pragma unroll
  for (int i = 0; i < 16; i++) o[i] = (_Float16)t[cg + i][n];
  _Float16* dst = &xt[((long)b * NPIX + n0 + n) * 256 + c0 + cg];
  *(float4*)dst = *(float4*)&o[0];
  *(float4*)(dst + 8) = *(float4*)&o[8];
}

// ---------------------------------------------------------------------------
// FUSED q-GEMM + column softmax over d. 2-phase prefetch double-buffered
// staging: STAGE(t+1) issued before ds_read/MFMA of tile t; the single
// __syncthreads (drains vmcnt+lgkm) at loop bottom is the only barrier.
// ---------------------------------------------------------------------------
__global__ __launch_bounds__(256) void q_gemm_softmax(const _Float16* __restrict__ Ahp,
                                                      const _Float16* __restrict__ Alp,
                                                      const _Float16* __restrict__ Bt,
                                                      _Float16* __restrict__ PT) {
  union alignas(16) QU {
    _Float16 st[2][3][128 * 32];  // [buf][Ah,Al,Bt] 48 KB dbuf staging
    _Float16 pt[128][128];        // 32 KB, epilogue P-tile (XOR-swizzled cols)
  };
  __shared__ QU u;
  const int tid = threadIdx.x;
  const int n0 = blockIdx.x * 128, m0 = blockIdx.y * 128;
  const int bz = blockIdx.z;
  const _Float16* Bp = Bt + (long)bz * NPIX * 256;
  const int wv = tid >> 6, l = tid & 63;
  const int r16 = l & 15, q = l >> 4;
  const int mb = (wv >> 1) * 64, nb = (wv & 1) * 64;
  const int r1 = tid >> 2;
  const int o1 = ((tid & 3) * 8) ^ (((r1 >> 1) & 3) * 8);
  const int r2 = r1 + 64;
  const int ldsc1 = (wv * 64) * 8;
  const int ldsc2 = (256 + wv * 64) * 8;
  const int q8 = (q * 8) ^ (((r16 >> 1) & 3) * 8);

  auto STAGE = [&](int buf, int kt) {
    const int k0 = kt * 32;
    async16(&u.st[buf][0][ldsc1], &Ahp[(long)(m0 + r1) * 256 + k0 + o1]);
    async16(&u.st[buf][0][ldsc2], &Ahp[(long)(m0 + r2) * 256 + k0 + o1]);
    async16(&u.st[buf][1][ldsc1], &Alp[(long)(m0 + r1) * 256 + k0 + o1]);
    async16(&u.st[buf][1][ldsc2], &Alp[(long)(m0 + r2) * 256 + k0 + o1]);
    async16(&u.st[buf][2][ldsc1], &Bp[(long)(n0 + r1) * 256 + k0 + o1]);
    async16(&u.st[buf][2][ldsc2], &Bp[(long)(n0 + r2) * 256 + k0 + o1]);
  };

  floatx4 acc[4][4];
#pragma unroll
  for (int i = 0; i < 4; i++)
#pragma unroll
    for (int j = 0; j < 4; j++) acc[i][j] = (floatx4){0.f, 0.f, 0.f, 0.f};

  STAGE(0, 0);
  __syncthreads();
  int cur = 0;
  for (int kt = 0; kt < 8; kt++) {
    if (kt < 7) STAGE(cur ^ 1, kt + 1);
    half8 fa[4], flo[4], fb[4];
#pragma unroll
    for (int i = 0; i < 4; i++) {
      fa[i] = *(const half8*)&u.st[cur][0][(mb + i * 16 + r16) * 32 + q8];
      flo[i] = *(const half8*)&u.st[cur][1][(mb + i * 16 + r16) * 32 + q8];
      fb[i] = *(const half8*)&u.st[cur][2][(nb + i * 16 + r16) * 32 + q8];
    }
#pragma unroll
    for (int i = 0; i < 4; i++)
#pragma unroll
      for (int j = 0; j < 4; j++) {
        acc[i][j] = __builtin_amdgcn_mfma_f32_16x16x32_f16(fa[i], fb[j], acc[i][j], 0, 0, 0);
        acc[i][j] = __builtin_amdgcn_mfma_f32_16x16x32_f16(flo[i], fb[j], acc[i][j], 0, 0, 0);
      }
    __syncthreads();
    cur ^= 1;
  }

  // ---- epilogue: per-column softmax over d (wave holds one head's 64 rows) ----
#pragma unroll
  for (int j = 0; j < 4; j++) {
    float s = 0.f;
#pragma unroll
    for (int i = 0; i < 4; i++)
#pragma unroll
      for (int t = 0; t < 4; t++) {
        float e = __expf(acc[i][j][t]);
        acc[i][j][t] = e;
        s += e;
      }
    s += __shfl_xor(s, 16, 64);
    s += __shfl_xor(s, 32, 64);
    const float rinv = 1.0f / s;
    const int nl = nb + j * 16 + r16;
    const int swz = (nl & 7) * 8;  // bank-spread: (q,nl&7) -> 32 distinct banks
#pragma unroll
    for (int i = 0; i < 4; i++) {
      half4 h4;
#pragma unroll
      for (int t = 0; t < 4; t++) h4[t] = (_Float16)(acc[i][j][t] * rinv);
      *(half4*)&u.pt[nl][(mb + i * 16 + q * 4) ^ swz] = h4;
    }
  }
  __syncthreads();
  // ---- dump P-tile: rows contiguous (PT row stride = 128 c), 1KB/wave-instr ----
  const int rbase = tid >> 4, c16 = tid & 15;
  _Float16* dst = PT + ((long)(bz * 2 + (m0 >> 7)) * NPIX + n0) * 128;
#pragma unroll
  for (int k = 0; k < 8; k++) {
    const int row = rbase + k * 16;
    const int chunk = c16 ^ (row & 7);
    float4 v = *(const float4*)&u.pt[row][chunk * 8];
    *(float4*)&dst[(long)row * 128 + c16 * 8] = v;
  }
}

// ---------------------------------------------------------------------------
// FUSED k/v GEMM + exp(k)@v^T context partials. Each block loops CPB=4
// n-chunks, accumulating the context partial in MFMA C-regs (c2) across
// chunks -> pbuf shrinks 4x (8.4 MB). 2-phase prefetch per chunk.
// ---------------------------------------------------------------------------
#define CPB 4
__global__ __launch_bounds__(256) void kv_ctx_gemm(const _Float16* __restrict__ Ahp,
                                                   const _Float16* __restrict__ Alp,
                                                   const _Float16* __restrict__ Bt,
                                                   float* __restrict__ pbuf,
                                                   float* __restrict__ rsbuf) {
  union alignas(16) KVU {
    _Float16 st[2][3][128 * 32];  // 48 KB dbuf staging
    _Float16 ev[128][136];        // 34 KB epilogue: rows 0..63 exp(k), 64..127 v
  };
  __shared__ KVU u;
  const int tid = threadIdx.x;
  const int cg = blockIdx.x;     // 0..7 chunk-group (4 chunks of 128 each)
  const int hi = blockIdx.y;     // head 0..3
  const int b = blockIdx.z;
  const _Float16* Bp = Bt + (long)b * NPIX * 256;
  const int wv = tid >> 6, l = tid & 63;
  const int r16 = l & 15, q = l >> 4;
  const int mb = (wv >> 1) * 64, nb = (wv & 1) * 64;
  const int r1 = tid >> 2;
  const int o1 = ((tid & 3) * 8) ^ (((r1 >> 1) & 3) * 8);
  const int ldsc1 = (wv * 64) * 8;
  const int ldsc2 = (256 + wv * 64) * 8;
  const int q8 = (q * 8) ^ (((r16 >> 1) & 3) * 8);
  // A rows: local 0..63 = k[head hi], 64..127 = v[head hi]
  const long gAk = (long)(256 + hi * 64 + r1) * 256;
  const long gAv = (long)(512 + hi * 64 + r1) * 256;

  auto STAGE = [&](int buf, int kt, int n0) {
    const int k0 = kt * 32;
    async16(&u.st[buf][0][ldsc1], &Ahp[gAk + k0 + o1]);
    async16(&u.st[buf][0][ldsc2], &Ahp[gAv + k0 + o1]);
    async16(&u.st[buf][1][ldsc1], &Alp[gAk + k0 + o1]);
    async16(&u.st[buf][1][ldsc2], &Alp[gAv + k0 + o1]);
    async16(&u.st[buf][2][ldsc1], &Bp[(long)(n0 + r1) * 256 + k0 + o1]);
    async16(&u.st[buf][2][ldsc2], &Bp[(long)(n0 + 64 + r1) * 256 + k0 + o1]);
  };

  floatx4 c2[4];
#pragma unroll
  for (int j = 0; j < 4; j++) c2[j] = (floatx4){0.f, 0.f, 0.f, 0.f};
  float rs = 0.f;

  for (int cs = 0; cs < CPB; cs++) {
    const int n0 = (cg * CPB + cs) * 128;
    floatx4 acc[4][4];
#pragma unroll
    for (int i = 0; i < 4; i++)
#pragma unroll
      for (int j = 0; j < 4; j++) acc[i][j] = (floatx4){0.f, 0.f, 0.f, 0.f};

    STAGE(0, 0, n0);
    __syncthreads();
    int cur = 0;
    for (int kt = 0; kt < 8; kt++) {
      if (kt < 7) STAGE(cur ^ 1, kt + 1, n0);
      half8 fa[4], flo[4], fb[4];
#pragma unroll
      for (int i = 0; i < 4; i++) {
        fa[i] = *(const half8*)&u.st[cur][0][(mb + i * 16 + r16) * 32 + q8];
        flo[i] = *(const half8*)&u.st[cur][1][(mb + i * 16 + r16) * 32 + q8];
        fb[i] = *(const half8*)&u.st[cur][2][(nb + i * 16 + r16) * 32 + q8];
      }
#pragma unroll
      for (int i = 0; i < 4; i++)
#pragma unroll
        for (int j = 0; j < 4; j++) {
          acc[i][j] = __builtin_amdgcn_mfma_f32_16x16x32_f16(fa[i], fb[j], acc[i][j], 0, 0, 0);
          acc[i][j] = __builtin_amdgcn_mfma_f32_16x16x32_f16(flo[i], fb[j], acc[i][j], 0, 0, 0);
        }
      __syncthreads();
      cur ^= 1;
    }

    // ---- epilogue: acc -> exp(k)/v fp16 tile in LDS (stride 136) ----
    const bool is_k = (mb == 0);
#pragma unroll
    for (int i = 0; i < 4; i++) {
      const int row = mb + i * 16 + q * 4;
#pragma unroll
      for (int j = 0; j < 4; j++) {
        const int col = nb + j * 16 + r16;
#pragma unroll
        for (int t = 0; t < 4; t++) {
          const float vv0 = acc[i][j][t];
          u.ev[row + t][col] = (_Float16)(is_k ? __expf(vv0) : vv0);
        }
      }
    }
    __syncthreads();

    // ---- context partial: c2[d][e] += sum_n exp(k[d][n]) v[e][n], K=128 ----
#pragma unroll
    for (int ks = 0; ks < 4; ks++) {
      half8 a = *(const half8*)&u.ev[wv * 16 + r16][ks * 32 + q * 8];
#pragma unroll
      for (int ii = 0; ii < 8; ii++) rs += (float)a[ii];
#pragma unroll
      for (int j = 0; j < 4; j++) {
        half8 bv = *(const half8*)&u.ev[64 + j * 16 + r16][ks * 32 + q * 8];
        c2[j] = __builtin_amdgcn_mfma_f32_16x16x32_f16(a, bv, c2[j], 0, 0, 0);
      }
    }
    __syncthreads();  // ev reads done before next chunk's STAGE overwrites
  }

  rs += __shfl_xor(rs, 16, 64);
  rs += __shfl_xor(rs, 32, 64);
  const int bh = b * 4 + hi;
  float* pp = pbuf + ((long)bh * 8 + cg) * 4096;
#pragma unroll
  for (int j = 0; j < 4; j++)
#pragma unroll
    for (int reg = 0; reg < 4; reg++)
      pp[(wv * 16 + q * 4 + reg) * 64 + j * 16 + r16] = c2[j][reg];
  if (l < 16) rsbuf[((long)bh * 8 + cg) * 64 + wv * 16 + r16] = rs;
}

// ---------------------------------------------------------------------------
// ctx[bh][4096] = sum over 8 chunk-group partials (deterministic, no atomics)
// ---------------------------------------------------------------------------
__global__ __launch_bounds__(256) void reduce_ctx(const float* __restrict__ pbuf,
                                                  float* __restrict__ ctx) {
  int g = blockIdx.x * 256 + threadIdx.x;  // 0..262143
  int bh = g >> 12, e = g & 4095;
  const float* pp = pbuf + ((long)bh * 8) * 4096 + e;
  float s = 0.f;
#pragma unroll
  for (int c = 0; c < 8; c++) s += pp[(long)c * 4096];
  ctx[g] = s;
}

// ---------------------------------------------------------------------------
// kinvz[bh*64+d] = 1 / sum over 8 chunk-group row-sums
// ---------------------------------------------------------------------------
__global__ __launch_bounds__(256) void zinv_kernel(const float* __restrict__ rsbuf,
                                                   float* __restrict__ kinvz) {
  int g = blockIdx.x * 256 + threadIdx.x;  // 0..4095 = bh*64 + d
  int bh = g >> 6, d = g & 63;
  const float* rp = rsbuf + (long)bh * 8 * 64 + d;
  float s = 0.f;
#pragma unroll
  for (int c = 0; c < 8; c++) s += rp[c * 64];
  kinvz[g] = 1.0f / s;
}

// ---------------------------------------------------------------------------
// M_b[c][h*64+d] = SCALE * invZ[bh][d] * sum_e w_out[c][h*64+e] * ctx[bh][d][e]
// (folds the attention d-contraction into the final GEMM's A-operand).
// ---------------------------------------------------------------------------
__global__ __launch_bounds__(256) void mctx_kernel(const float* __restrict__ w_out,
                                                   const float* __restrict__ ctx,
                                                   const float* __restrict__ kinvz,
                                                   _Float16* __restrict__ Mhi,
                                                   _Float16* __restrict__ Mlo) {
  __shared__ float sctxT[64][65];  // [e][d], +1 pad
  const int cq = blockIdx.x, h = blockIdx.y, b = blockIdx.z;
  const int bh = b * 4 + h;
  const float* cp = ctx + (long)bh * 4096;  // [d][e]
  const int tid = threadIdx.x;
  {
    const int d = tid >> 2, e0 = (tid & 3) * 16;
#pragma unroll
    for (int k = 0; k < 4; k++) {
      float4 v = *(const float4*)&cp[d * 64 + e0 + k * 4];
      sctxT[e0 + k * 4 + 0][d] = v.x;
      sctxT[e0 + k * 4 + 1][d] = v.y;
      sctxT[e0 + k * 4 + 2][d] = v.z;
      sctxT[e0 + k * 4 + 3][d] = v.w;
    }
  }
  __syncthreads();
  const int c = cq * 64 + (tid >> 2);
  const int d0 = (tid & 3) * 16;
  const float* wp = w_out + (long)c * 256 + h * 64;
  float acc[16];
#pragma unroll
  for (int i = 0; i < 16; i++) acc[i] = 0.f;
#pragma unroll
  for (int e4 = 0; e4 < 16; e4++) {
    float4 wv = *(const float4*)&wp[e4 * 4];
#pragma unroll
    for (int u2 = 0; u2 < 4; u2++) {
      const float we = ((const float*)&wv)[u2];
      const int e = e4 * 4 + u2;
#pragma unroll
      for (int dd = 0; dd < 16; dd++) acc[dd] = fmaf(we, sctxT[e][d0 + dd], acc[dd]);
    }
  }
  alignas(16) _Float16 hi16[16], lo16[16];
#pragma unroll
  for (int k4 = 0; k4 < 4; k4++) {
    float4 zv = *(const float4*)&kinvz[bh * 64 + d0 + k4 * 4];
#pragma unroll
    for (int u2 = 0; u2 < 4; u2++) {
      const int dd = k4 * 4 + u2;
      float v = acc[dd] * (SCALE * ((const float*)&zv)[u2]);
      _Float16 hh = (_Float16)v;
      hi16[dd] = hh;
      lo16[dd] = (_Float16)(v - (float)hh);
    }
  }
  _Float16* mh = Mhi + ((long)b * 256 + c) * 256 + h * 64 + d0;
  _Float16* ml = Mlo + ((long)b * 256 + c) * 256 + h * 64 + d0;
#pragma unroll
  for (int k = 0; k < 2; k++) {
    *(float4*)&mh[k * 8] = *(float4*)&hi16[k * 8];
    *(float4*)&ml[k * 8] = *(float4*)&lo16[k * 8];
  }
}

// ---------------------------------------------------------------------------
// final GEMM: out[b][256][4096] = (Mhi+Mlo)[b] @ PT[b]^T + b_out
// B layout: PT[b][s][4096][128], s = K-half (kt>>2). 2-phase prefetch.
// ---------------------------------------------------------------------------
__global__ __launch_bounds__(256) void out_gemm(const _Float16* __restrict__ Mhi,
                                                const _Float16* __restrict__ Mlo,
                                                const _Float16* __restrict__ PT,
                                                float* __restrict__ C,
                                                const float* __restrict__ bias) {
  __shared__ _Float16 st[2][3][128 * 32];  // 48 KB dbuf staging
  const int tid = threadIdx.x;
  const int n0 = blockIdx.x * 128, m0 = blockIdx.y * 128;
  const int b = blockIdx.z;
  const _Float16* Ah = Mhi + (long)b * 65536;
  const _Float16* Al = Mlo + (long)b * 65536;
  float* Cp = C + (long)b * 256 * NPIX;
  const int wv = tid >> 6, l = tid & 63;
  const int r16 = l & 15, q = l >> 4;
  const int mb = (wv >> 1) * 64, nb = (wv & 1) * 64;
  const int r1 = tid >> 2;
  const int o1 = ((tid & 3) * 8) ^ (((r1 >> 1) & 3) * 8);
  const int r2 = r1 + 64;
  const int ldsc1 = (wv * 64) * 8;
  const int ldsc2 = (256 + wv * 64) * 8;
  const int q8 = (q * 8) ^ (((r16 >> 1) & 3) * 8);

  auto STAGE = [&](int buf, int kt) {
    const int k0 = kt * 32;
    async16(&st[buf][0][ldsc1], &Ah[(long)(m0 + r1) * 256 + k0 + o1]);
    async16(&st[buf][0][ldsc2], &Ah[(long)(m0 + r2) * 256 + k0 + o1]);
    async16(&st[buf][1][ldsc1], &Al[(long)(m0 + r1) * 256 + k0 + o1]);
    async16(&st[buf][1][ldsc2], &Al[(long)(m0 + r2) * 256 + k0 + o1]);
    const _Float16* Bk = PT + ((long)(b * 2 + (kt >> 2)) * NPIX + n0) * 128;
    async16(&st[buf][2][ldsc1], &Bk[(long)r1 * 128 + (kt & 3) * 32 + o1]);
    async16(&st[buf][2][ldsc2], &Bk[(long)(r1 + 64) * 128 + (kt & 3) * 32 + o1]);
  };

  floatx4 acc[4][4];
#pragma unroll
  for (int i = 0; i < 4; i++)
#pragma unroll
    for (int j = 0; j < 4; j++) acc[i][j] = (floatx4){0.f, 0.f, 0.f, 0.f};

  STAGE(0, 0);
  __syncthreads();
  int cur = 0;
  for (int kt = 0; kt < 8; kt++) {
    if (kt < 7) STAGE(cur ^ 1, kt + 1);
    half8 fa[4], flo[4], fb[4];
#pragma unroll
    for (int i = 0; i < 4; i++) {
      fa[i] = *(const half8*)&st[cur][0][(mb + i * 16 + r16) * 32 + q8];
      flo[i] = *(const half8*)&st[cur][1][(mb + i * 16 + r16) * 32 + q8];
      fb[i] = *(const half8*)&st[cur][2][(nb + i * 16 + r16) * 32 + q8];
    }
#pragma unroll
    for (int i = 0; i < 4; i++)
#pragma unroll
      for (int j = 0; j < 4; j++) {
        acc[i][j] = __builtin_amdgcn_mfma_f32_16x16x32_f16(fa[i], fb[j], acc[i][j], 0, 0, 0);
        acc[i][j] = __builtin_amdgcn_mfma_f32_16x16x32_f16(flo[i], fb[j], acc[i][j], 0, 0, 0);
      }
    __syncthreads();
    cur ^= 1;
  }
#pragma unroll
  for (int i = 0; i < 4; i++) {
    const int mrow = m0 + mb + i * 16 + q * 4;
#pragma unroll
    for (int t = 0; t < 4; t++) {
      float bz = bias[mrow + t];
#pragma unroll
      for (int j = 0; j < 4; j++) {
        Cp[(long)(mrow + t) * NPIX + n0 + nb + j * 16 + r16] = acc[i][j][t] + bz;
      }
    }
  }
}

extern "C" void kernel_launch(void* const* d_in, const int* in_sizes, int n_in,
                              void* d_out, int out_size, void* d_ws, size_t ws_size,
                              hipStream_t stream) {
  const float* x = (const float*)d_in[0];      // [16][256][4096]
  const float* w_qkv = (const float*)d_in[1];  // [768][256]
  const float* w_out = (const float*)d_in[2];  // [256][256]
  const float* b_out = (const float*)d_in[3];  // [256]
  float* out = (float*)d_out;                  // [16][256][4096]

  // d_ws layout (all live ranges disjoint in time or space):
  _Float16* PT = (_Float16*)d_ws;                           // [16][2][4096][128] = 32 MB
  float* ctx = (float*)(PT + (long)16 * 2 * NPIX * 128);    // 64bh * 4096 = 1 MB
  float* kinvz = ctx + 64 * 4096;                           // 16 KB
  float* rsbuf = kinvz + 4096;                              // 64bh*8cg*64 = 128 KB
  _Float16* wq_hi = (_Float16*)(rsbuf + 64 * 8 * 64);
  _Float16* wq_lo = wq_hi + 768 * 256;
  _Float16* Mhi = wq_lo + 768 * 256;                        // 16*256*256 fp16 = 2 MB
  _Float16* Mlo = Mhi + 16 * 256 * 256;                     // 2 MB
  // d_out scratch (dead until out_gemm writes it):
  _Float16* xt = (_Float16*)d_out;                          // [0..32MB)
  float* pbuf = (float*)d_out + (1 << 23);                  // [32MB..): 64bh*8cg*4096 = 8.4 MB

  split16_kernel<<<768, 256, 0, stream>>>(w_qkv, wq_hi, wq_lo, 768 * 256);
  transpose16_kernel<<<dim3(64, 4, 16), 256, 0, stream>>>(x, xt);
  // fused k/v GEMM + exp(k)@v^T context partials (4 chunks/block, reg-accum)
  kv_ctx_gemm<<<dim3(8, 4, 16), 256, 0, stream>>>(wq_hi, wq_lo, xt, pbuf, rsbuf);
  reduce_ctx<<<1024, 256, 0, stream>>>(pbuf, ctx);
  zinv_kernel<<<16, 256, 0, stream>>>(rsbuf, kinvz);
  // fused q GEMM + softmax -> P fp16 (q fp32 never touches HBM)
  q_gemm_softmax<<<dim3(32, 2, 16), 256, 0, stream>>>(wq_hi, wq_lo, xt, PT);
  // M_b = w_out @ ctx^T * diag(SCALE*invZ): attention folded into final A
  mctx_kernel<<<dim3(4, 4, 16), 256, 0, stream>>>(w_out, ctx, kinvz, Mhi, Mlo);
  // final = M_b @ P_b + b_out
  out_gemm<<<dim3(32, 2, 16), 256, 0, stream>>>(Mhi, Mlo, PT, out, b_out);
}